// Round 2
// baseline (538.136 us; speedup 1.0000x reference)
//
#include <hip/hip_runtime.h>
#include <hip/hip_bf16.h>

// InterestEvolve: attention-modulated GRU scan. B=2048, T=200, D=128, U=128.
//
// R10 = R9 + hardened raw-barrier sync (sched_barrier(0) pins LDS ops on
// both sides of each s_barrier — rule #18: hipcc may hoist ops past
// inline-asm waitcnt / raw s_barrier; __syncthreads-style safety without
// its vmcnt(0) drain).
//
// R9 design (unchanged):
//  - 4 waves x 32 gatecols (was 8x16): halves duplicated LDS B-fragment
//    reads (h/rh fragments are identical across waves; only weights differ).
//  - x and Att loaded GLOBAL-DIRECT with register prefetch (x: 1 step ahead,
//    Att: 3 ahead), bf16-converted in-register. No x_sm/a_sm, no staging.
//  - Barriers wait lgkmcnt only -> prefetch loads stay in flight.
//  - Step 0 special-cased (h=0 => x-part only): no LDS zero-init needed.
// Weights 192 VGPR; biases preloaded into MFMA C; __launch_bounds__(256,1)
// gives the 512-VGPR budget (1 wave/SIMD). 128 blocks x 256 threads.

#define T_LEN 200
#define D_DIM 128
#define U_DIM 128
#define BM    16
#define KCS   136          // ushorts per kchunk slot-row: 16 batch*8 + 8 pad
#define XSTEP (16 * KCS)   // ushorts per h/rh buffer (2176)

typedef __attribute__((ext_vector_type(8))) short bf16x8;
typedef __attribute__((ext_vector_type(4))) float f32x4;
typedef __attribute__((ext_vector_type(4))) unsigned int uint4v;

#define MFMA __builtin_amdgcn_mfma_f32_16x16x32_bf16

static __device__ __forceinline__ unsigned short f2bf(float f) {
    unsigned int u = __builtin_bit_cast(unsigned int, f);
    u += 0x7fffu + ((u >> 16) & 1u);       // round-to-nearest-even
    return (unsigned short)(u >> 16);
}
static __device__ __forceinline__ unsigned int pkbf2(float a, float b) {
    float2 t; t.x = a; t.y = b;
    __hip_bfloat162 v = __float22bfloat162_rn(t);   // v_cvt_pk_bf16_f32
    unsigned int u; __builtin_memcpy(&u, &v, 4);
    return u;
}
static __device__ __forceinline__ bf16x8 pack8bf(f32x4 lo, f32x4 hi) {
    uint4v v;
    v[0] = pkbf2(lo[0], lo[1]); v[1] = pkbf2(lo[2], lo[3]);
    v[2] = pkbf2(hi[0], hi[1]); v[3] = pkbf2(hi[2], hi[3]);
    return __builtin_bit_cast(bf16x8, v);
}
static __device__ __forceinline__ float fast_exp2(float x) {
#if __has_builtin(__builtin_amdgcn_exp2f)
    return __builtin_amdgcn_exp2f(x);
#else
    return exp2f(x);
#endif
}
static __device__ __forceinline__ float fast_rcp(float x) {
#if __has_builtin(__builtin_amdgcn_rcpf)
    return __builtin_amdgcn_rcpf(x);
#else
    return 1.0f / x;
#endif
}
// Barrier that waits ONLY on LDS ops (h/rh handoff) and leaves the global
// prefetch loads in flight (no vmcnt(0) drain, unlike __syncthreads()).
// sched_barrier(0) on both sides: pre-barrier ds_write can't sink, and
// post-barrier ds_read can't hoist (rule #18 hazard).
static __device__ __forceinline__ void block_sync_lds() {
    asm volatile("s_waitcnt lgkmcnt(0)" ::: "memory");
    __builtin_amdgcn_sched_barrier(0);
    __builtin_amdgcn_s_barrier();
    __builtin_amdgcn_sched_barrier(0);
}

__global__ __launch_bounds__(256, 1)
void gru_scan_kernel(const float* __restrict__ X,    // (B,T,D)
                     const float* __restrict__ Att,  // (B,T,1)
                     const float* __restrict__ Wu, const float* __restrict__ bu,
                     const float* __restrict__ Wr, const float* __restrict__ br,
                     const float* __restrict__ Wh, const float* __restrict__ bh,
                     float* __restrict__ out)        // (B,U)
{
    __shared__ __align__(16) unsigned short h_bf[XSTEP];   // 4352 B
    __shared__ __align__(16) unsigned short rh_bf[XSTEP];  // 4352 B

    const int tid  = threadIdx.x;
    const int wave = tid >> 6;    // 0..3, owns gatecols [32*wave, 32*wave+32)
    const int lane = tid & 63;
    const int q    = lane >> 4;
    const int ln   = lane & 15;
    const int b0   = blockIdx.x * BM;

    const float INVLN2 = 1.4426950408889634f;

    // ---- Weight A-fragments: 2 col-tiles x 8 k-tiles per matrix, bf16,
    // ln2-prescaled. lane holds gatecol m = ln (tile base 32w+16tl),
    // k = 32*kt + 8*q + j. GEMM1 k: [h|x] rows. GEMM2 k: [x|r*h] rows.
    bf16x8 wu[2][8], wr[2][8], wh[2][8];            // 192 VGPRs
    f32x4 nbu[2], nbr[2], bh2[2];                   // C-operand bias preload
    #pragma unroll
    for (int tl = 0; tl < 2; ++tl) {
        const int tb = 32 * wave + 16 * tl;
        const int c  = tb + ln;
        const f32x4 bu4 = *(const f32x4*)&bu[tb + 4 * q];
        const f32x4 br4 = *(const f32x4*)&br[tb + 4 * q];
        const f32x4 bh4 = *(const f32x4*)&bh[tb + 4 * q];
        #pragma unroll
        for (int r = 0; r < 4; ++r) {
            nbu[tl][r] = -bu4[r] * INVLN2;
            nbr[tl][r] = -br4[r] * INVLN2;
            bh2[tl][r] = 2.0f * bh4[r] * INVLN2;
        }
        #pragma unroll
        for (int kt = 0; kt < 8; ++kt) {
            const int k0 = 32 * kt + 8 * q;
            bf16x8 vu, vr, vh;
            #pragma unroll
            for (int j = 0; j < 8; ++j) {
                vu[j] = (short)f2bf(Wu[(k0 + j) * U_DIM + c] * -INVLN2);
                vr[j] = (short)f2bf(Wr[(k0 + j) * U_DIM + c] * -INVLN2);
                vh[j] = (short)f2bf(Wh[(k0 + j) * U_DIM + c] * (2.0f * INVLN2));
            }
            wu[tl][kt] = vu; wr[tl][kt] = vr; wh[tl][kt] = vh;
        }
    }

    // per-lane global source pointers (all 4 waves read the same x lines -> L1)
    const float* xrow = X + (size_t)(b0 + ln) * T_LEN * D_DIM + 8 * q;
    const float* arow = Att + (size_t)(b0 + ln) * T_LEN;

    // x prefetch registers: 8 f32x4 = one step's B-fragments (fp32)
    f32x4 px[8];
    #pragma unroll
    for (int kt = 0; kt < 4; ++kt) {
        px[2 * kt]     = *(const f32x4*)(xrow + 32 * kt);
        px[2 * kt + 1] = *(const f32x4*)(xrow + 32 * kt + 4);
    }
    const float a0 = arow[0];
    float attA = arow[1], attB = arow[2], attC = arow[3];   // 3-deep pipeline

    float hreg[2][4];   // fp32 h: batch=ln, gatecol = 32w+16tl+4q+r

    const int c8base = (4 * wave) * KCS + ln * 8 + (q & 1) * 4;
    const int c8q    = (q >> 1) * KCS;

    // ---- step 0: h = 0 -> pure x-part (no h-part, no rh-part, no LDS read)
    {
        bf16x8 xf[4];
        #pragma unroll
        for (int kt = 0; kt < 4; ++kt) xf[kt] = pack8bf(px[2 * kt], px[2 * kt + 1]);
        // issue x loads for t=1
        #pragma unroll
        for (int kt = 0; kt < 4; ++kt) {
            px[2 * kt]     = *(const f32x4*)(xrow + D_DIM + 32 * kt);
            px[2 * kt + 1] = *(const f32x4*)(xrow + D_DIM + 32 * kt + 4);
        }
        #pragma unroll
        for (int tl = 0; tl < 2; ++tl) {
            f32x4 xu = nbu[tl], xh = bh2[tl];
            #pragma unroll
            for (int kt = 0; kt < 4; ++kt) {
                xu = MFMA(wu[tl][kt + 4], xf[kt], xu, 0, 0, 0);
                xh = MFMA(wh[tl][kt],     xf[kt], xh, 0, 0, 0);
            }
            #pragma unroll
            for (int r = 0; r < 4; ++r) {
                float u  = fast_rcp(1.0f + fast_exp2(xu[r])) * a0;          // sigmoid*a
                float hh = 1.0f - 2.0f * fast_rcp(1.0f + fast_exp2(xh[r])); // tanh
                hreg[tl][r] = u * hh;                                        // (1-u)*0
            }
            uint2 wv; wv.x = pkbf2(hreg[tl][0], hreg[tl][1]);
            wv.y = pkbf2(hreg[tl][2], hreg[tl][3]);
            *(uint2*)&h_bf[c8base + c8q + 2 * tl * KCS] = wv;
        }
    }
    block_sync_lds();

    for (int t = 1; t < T_LEN; ++t) {
        // ---------------- region 1 ----------------
        bf16x8 hf[4];     // h(t-1) fragments, identical for all waves
        #pragma unroll
        for (int kt = 0; kt < 4; ++kt)
            hf[kt] = *(const bf16x8*)&h_bf[(4 * kt + q) * KCS + ln * 8];

        // convert prefetched x(t) (waits vmcnt on px only), then reissue px
        bf16x8 xf[4];
        #pragma unroll
        for (int kt = 0; kt < 4; ++kt) xf[kt] = pack8bf(px[2 * kt], px[2 * kt + 1]);
        {
            const int tn = (t + 1 < T_LEN) ? t + 1 : T_LEN - 1;
            const float* xs = xrow + (size_t)tn * D_DIM;
            #pragma unroll
            for (int kt = 0; kt < 4; ++kt) {
                px[2 * kt]     = *(const f32x4*)(xs + 32 * kt);
                px[2 * kt + 1] = *(const f32x4*)(xs + 32 * kt + 4);
            }
        }
        const float a_att = attA;
        attA = attB; attB = attC;
        attC = arow[(t + 3 < T_LEN) ? t + 3 : T_LEN - 1];

        // x-part chains (independent of hf; fill the ds_read latency)
        f32x4 xr[2], xu[2], xh[2];
        #pragma unroll
        for (int tl = 0; tl < 2; ++tl) {
            xr[tl] = nbr[tl]; xu[tl] = nbu[tl]; xh[tl] = bh2[tl];
            #pragma unroll
            for (int kt = 0; kt < 4; ++kt) {
                xr[tl] = MFMA(wr[tl][kt + 4], xf[kt], xr[tl], 0, 0, 0);
                xu[tl] = MFMA(wu[tl][kt + 4], xf[kt], xu[tl], 0, 0, 0);
                xh[tl] = MFMA(wh[tl][kt],     xf[kt], xh[tl], 0, 0, 0);
            }
        }
        // r h-part (critical, 2+2 partials per tile); u h-part chains onto xu
        f32x4 ra[2], rb[2];
        #pragma unroll
        for (int tl = 0; tl < 2; ++tl) {
            ra[tl] = MFMA(wr[tl][0], hf[0], (f32x4)0.0f, 0, 0, 0);
            rb[tl] = MFMA(wr[tl][2], hf[2], (f32x4)0.0f, 0, 0, 0);
            ra[tl] = MFMA(wr[tl][1], hf[1], ra[tl], 0, 0, 0);
            rb[tl] = MFMA(wr[tl][3], hf[3], rb[tl], 0, 0, 0);
            #pragma unroll
            for (int kt = 0; kt < 4; ++kt)
                xu[tl] = MFMA(wu[tl][kt], hf[kt], xu[tl], 0, 0, 0);
        }
        // r sigmoid; r*h -> LDS (one ds_write_b64 per tile)
        #pragma unroll
        for (int tl = 0; tl < 2; ++tl) {
            float rh[4];
            #pragma unroll
            for (int r = 0; r < 4; ++r) {
                float zr = xr[tl][r] + ra[tl][r] + rb[tl][r];   // = -z_r/ln2
                float rv = fast_rcp(1.0f + fast_exp2(zr));      // sigmoid
                rh[r] = rv * hreg[tl][r];
            }
            uint2 wv; wv.x = pkbf2(rh[0], rh[1]); wv.y = pkbf2(rh[2], rh[3]);
            *(uint2*)&rh_bf[c8base + c8q + 2 * tl * KCS] = wv;
        }
        block_sync_lds();   // rh handoff (px/att loads stay in flight)

        // ---------------- region 2 ----------------
        bf16x8 rf[4];
        #pragma unroll
        for (int kt = 0; kt < 4; ++kt)
            rf[kt] = *(const bf16x8*)&rh_bf[(4 * kt + q) * KCS + ln * 8];

        // u gate (VALU, fills rf latency)
        float uq[2][4];
        #pragma unroll
        for (int tl = 0; tl < 2; ++tl)
            #pragma unroll
            for (int r = 0; r < 4; ++r)
                uq[tl][r] = fast_rcp(1.0f + fast_exp2(xu[tl][r])) * a_att;

        // candidate rh-part (critical, 2+2, seeded with ready x-part)
        #pragma unroll
        for (int tl = 0; tl < 2; ++tl) {
            f32x4 ha = xh[tl], hb = (f32x4)0.0f;
            ha = MFMA(wh[tl][4], rf[0], ha, 0, 0, 0);
            hb = MFMA(wh[tl][6], rf[2], hb, 0, 0, 0);
            ha = MFMA(wh[tl][5], rf[1], ha, 0, 0, 0);
            hb = MFMA(wh[tl][7], rf[3], hb, 0, 0, 0);
            #pragma unroll
            for (int r = 0; r < 4; ++r) {
                float z  = ha[r] + hb[r];                                // = 2*z_h/ln2
                float hh = 1.0f - 2.0f * fast_rcp(1.0f + fast_exp2(z));  // tanh
                float ho = hreg[tl][r];
                hreg[tl][r] = ho + uq[tl][r] * (hh - ho);                // u*hh+(1-u)*h
            }
            uint2 wv; wv.x = pkbf2(hreg[tl][0], hreg[tl][1]);
            wv.y = pkbf2(hreg[tl][2], hreg[tl][3]);
            *(uint2*)&h_bf[c8base + c8q + 2 * tl * KCS] = wv;
        }
        block_sync_lds();   // h handoff
    }

    // ---- store h_final: 4 consecutive gatecols per thread per tile ----
    #pragma unroll
    for (int tl = 0; tl < 2; ++tl) {
        f32x4 v;
        #pragma unroll
        for (int r = 0; r < 4; ++r) v[r] = hreg[tl][r];
        *(f32x4*)&out[(size_t)(b0 + ln) * U_DIM + 32 * wave + 16 * tl + 4 * q] = v;
    }
}

extern "C" void kernel_launch(void* const* d_in, const int* in_sizes, int n_in,
                              void* d_out, int out_size, void* d_ws, size_t ws_size,
                              hipStream_t stream) {
    const float* X   = (const float*)d_in[0];
    const float* Att = (const float*)d_in[1];
    const float* Wu  = (const float*)d_in[2];
    const float* bu  = (const float*)d_in[3];
    const float* Wr  = (const float*)d_in[4];
    const float* br  = (const float*)d_in[5];
    const float* Wh  = (const float*)d_in[6];
    const float* bh  = (const float*)d_in[7];
    float* out = (float*)d_out;

    gru_scan_kernel<<<dim3(2048 / BM), dim3(256), 0, stream>>>(
        X, Att, Wu, bu, Wr, br, Wh, bh, out);
}